// Round 11
// baseline (2339.390 us; speedup 1.0000x reference)
//
#include <hip/hip_runtime.h>
#include <hip/hip_bf16.h>

// RESOLVED (R10): d_out is FLOAT32. The harness compares against a
// bf16-ROUNDED np reference (hence bf16-grid absmax values), but reads d_out
// via the float32 path. Nine rounds of "stuck" absmax were my bf16 stores
// being misread as packed float32 pairs. All inputs fp32, edges int32,
// final layer NOT relu'd (R7). Pipeline below unchanged from R2 except the
// final store is float32.

__device__ __forceinline__ float leaky02(float x) { return x > 0.0f ? x : 0.2f * x; }

#define R_CAP 6400  // nodes per bin block; 16 blocks cover N=100000

// ---------- CSR build (LDS atomics only) ----------
__global__ __launch_bounds__(1024) void count_bin_kernel(
    const int* __restrict__ dst, int* __restrict__ cnt, int n, int ne) {
  __shared__ int cnts[R_CAP];
  const int lo = blockIdx.x * R_CAP;
  const int hi = min(lo + R_CAP, n);
  for (int i = threadIdx.x; i < R_CAP; i += 1024) cnts[i] = 0;
  __syncthreads();
  for (int e = threadIdx.x; e < ne; e += 1024) {
    int d = dst[e];
    if (d >= lo && d < hi) atomicAdd(&cnts[d - lo], 1);
  }
  __syncthreads();
  for (int i = threadIdx.x; i < hi - lo; i += 1024) cnt[lo + i] = cnts[i];
}

__global__ __launch_bounds__(1024) void scan1_kernel(int* __restrict__ cnt, int* __restrict__ bsums, int n) {
  __shared__ int s[1024];
  int gid = blockIdx.x * 1024 + threadIdx.x;
  int v = (gid < n) ? cnt[gid] : 0;
  s[threadIdx.x] = v;
  __syncthreads();
  for (int off = 1; off < 1024; off <<= 1) {
    int t = (threadIdx.x >= off) ? s[threadIdx.x - off] : 0;
    __syncthreads();
    s[threadIdx.x] += t;
    __syncthreads();
  }
  if (gid < n) cnt[gid] = s[threadIdx.x] - v;  // exclusive
  if (threadIdx.x == 1023) bsums[blockIdx.x] = s[1023];
}

__global__ __launch_bounds__(1024) void scan2_kernel(int* __restrict__ bsums, int nb) {
  __shared__ int s[1024];
  int v = (threadIdx.x < nb) ? bsums[threadIdx.x] : 0;
  s[threadIdx.x] = v;
  __syncthreads();
  for (int off = 1; off < 1024; off <<= 1) {
    int t = (threadIdx.x >= off) ? s[threadIdx.x - off] : 0;
    __syncthreads();
    s[threadIdx.x] += t;
    __syncthreads();
  }
  if (threadIdx.x < nb) bsums[threadIdx.x] = s[threadIdx.x] - v;
}

__global__ __launch_bounds__(1024) void scan3_kernel(
    const int* __restrict__ excl, const int* __restrict__ bsums,
    int* __restrict__ rowptr, int n, int ne) {
  int gid = blockIdx.x * 1024 + threadIdx.x;
  if (gid < n) rowptr[gid] = excl[gid] + bsums[blockIdx.x];
  if (gid == 0) rowptr[n] = ne;
}

__global__ __launch_bounds__(1024) void scatter_bin_kernel(
    const int* __restrict__ src, const int* __restrict__ dst,
    const int* __restrict__ rowptr, int* __restrict__ csr, int n, int ne) {
  __shared__ int cur[R_CAP];
  const int lo = blockIdx.x * R_CAP;
  const int hi = min(lo + R_CAP, n);
  for (int i = threadIdx.x; i < hi - lo; i += 1024) cur[i] = rowptr[lo + i];
  __syncthreads();
  for (int e = threadIdx.x; e < ne; e += 1024) {
    int d = dst[e];
    if (d >= lo && d < hi) {
      int pos = atomicAdd(&cur[d - lo], 1);  // LDS atomic
      csr[pos] = src[e];                     // disjoint plain store
    }
  }
}

__global__ void dinv_kernel(const int* __restrict__ rowptr, float* __restrict__ dinv, int n) {
  int i = blockIdx.x * 256 + threadIdx.x;
  if (i < n) dinv[i] = rsqrtf((float)(rowptr[i + 1] - rowptr[i] + 1));  // +1 self-loop
}

// ---------- dense matmul: C[n,64] = A[n,K] @ W[K,64], optional per-row dinv scale ----------
template<int K, bool SCALE>
__global__ __launch_bounds__(256) void matmul_kernel(
    const float* __restrict__ A, const float* __restrict__ W,
    const float* __restrict__ dinv, float* __restrict__ C, int n) {
  __shared__ float sW[K * 64];
  __shared__ float sA[16 * (K + 1)];
  const int tid = threadIdx.x;
  const int row0 = blockIdx.x * 16;
  for (int i = tid; i < K * 64; i += 256) sW[i] = W[i];
  for (int i = tid; i < 16 * K; i += 256) {
    int r = i / K, k = i - r * K;
    int row = row0 + r;
    sA[r * (K + 1) + k] = (row < n) ? A[(long)row * K + k] : 0.0f;
  }
  __syncthreads();
  const int r = tid >> 4;
  const int c4 = (tid & 15) * 4;
  float4 acc = make_float4(0.f, 0.f, 0.f, 0.f);
  const float* ap = &sA[r * (K + 1)];
#pragma unroll 16
  for (int k = 0; k < K; ++k) {
    float a = ap[k];
    float4 w = *reinterpret_cast<const float4*>(&sW[k * 64 + c4]);
    acc.x = fmaf(a, w.x, acc.x);
    acc.y = fmaf(a, w.y, acc.y);
    acc.z = fmaf(a, w.z, acc.z);
    acc.w = fmaf(a, w.w, acc.w);
  }
  int row = row0 + r;
  if (row < n) {
    float s = SCALE ? dinv[row] : 1.0f;
    float4 o = make_float4(acc.x * s, acc.y * s, acc.z * s, acc.w * s);
    *reinterpret_cast<float4*>(&C[(long)row * 64 + c4]) = o;
  }
}

// ---------- fused GCN aggregate + epilogue: one wave per node, lane = channel ----------
template<bool RELU>
__global__ __launch_bounds__(256) void gcn_layer_kernel(
    const int* __restrict__ rowptr, const int* __restrict__ csr,
    const float* __restrict__ hs, const float* __restrict__ dinv,
    const float* __restrict__ bias, float* __restrict__ out, int n) {
  int node = blockIdx.x * 4 + (threadIdx.x >> 6);
  if (node >= n) return;
  int lane = threadIdx.x & 63;
  int beg = rowptr[node], end = rowptr[node + 1];
  float acc = hs[(long)node * 64 + lane];  // self-loop (hs pre-scaled by dinv)
  for (int j = beg; j < end; ++j) {
    int s = csr[j];
    acc += hs[(long)s * 64 + lane];
  }
  float v = dinv[node] * acc + bias[lane];
  if (RELU) v = fmaxf(v, 0.0f);
  out[(long)node * 64 + lane] = v;
}

// ---------- GAT per-node attention logits ----------
__global__ void gat_alpha_kernel(
    const float* __restrict__ hg, const float* __restrict__ att_src, const float* __restrict__ att_dst,
    float* __restrict__ asrc, float* __restrict__ adst, int total) {
  int i = blockIdx.x * 256 + threadIdx.x;
  if (i >= total) return;
  int nrow = i >> 3, h = i & 7;
  const float* hp = &hg[(long)nrow * 64 + h * 8];
  float ss = 0.f, dd = 0.f;
#pragma unroll
  for (int c = 0; c < 8; ++c) {
    float v = hp[c];
    ss = fmaf(v, att_src[h * 8 + c], ss);
    dd = fmaf(v, att_dst[h * 8 + c], dd);
  }
  asrc[i] = ss;
  adst[i] = dd;
}

// ---------- fused GAT: in-wave softmax denom + weighted aggregation + relu ----------
__global__ __launch_bounds__(256) void gat_layer_kernel(
    const int* __restrict__ rowptr, const int* __restrict__ csr,
    const float* __restrict__ hg, const float* __restrict__ asrc,
    const float* __restrict__ adst, const float* __restrict__ bg,
    float* __restrict__ out, int n) {
  int node = blockIdx.x * 4 + (threadIdx.x >> 6);
  if (node >= n) return;
  int lane = threadIdx.x & 63;
  int beg = rowptr[node], end = rowptr[node + 1];
  // phase 1: softmax denominator per head; lane role h = lane&7, jj = lane>>3
  int h1 = lane & 7, jj = lane >> 3;
  float adn1 = adst[node * 8 + h1];
  float zp = 0.f;
  for (int j = beg + jj; j < end; j += 8) {
    int s = csr[j];
    zp += __expf(leaky02(asrc[s * 8 + h1] + adn1));
  }
  zp += __shfl_xor(zp, 8);
  zp += __shfl_xor(zp, 16);
  zp += __shfl_xor(zp, 32);
  zp += __expf(leaky02(asrc[node * 8 + h1] + adn1));  // self-loop term
  // phase 2: lane = channel, head h2 = lane>>3; z[h2] lives in lane (lane>>3)
  float rz = 1.0f / __shfl(zp, lane >> 3);
  int h2 = lane >> 3;
  float adn2 = adst[node * 8 + h2];
  float acc = 0.f;
  for (int j = beg; j < end; ++j) {
    int s = csr[j];
    float alpha = __expf(leaky02(asrc[s * 8 + h2] + adn2)) * rz;
    acc = fmaf(alpha, hg[(long)s * 64 + lane], acc);
  }
  float aself = __expf(leaky02(asrc[node * 8 + h2] + adn2)) * rz;
  acc = fmaf(aself, hg[(long)node * 64 + lane], acc);
  out[(long)node * 64 + lane] = fmaxf(acc + bg[lane], 0.0f);
}

extern "C" void kernel_launch(void* const* d_in, const int* in_sizes, int n_in,
                              void* d_out, int out_size, void* d_ws, size_t ws_size,
                              hipStream_t stream) {
  const float* x  = (const float*)d_in[0];
  const int* ei   = (const int*)d_in[1];
  const float* W0 = (const float*)d_in[2];
  const float* b0 = (const float*)d_in[3];
  const float* Wg = (const float*)d_in[4];
  const float* av = (const float*)d_in[5];
  const float* aw = (const float*)d_in[6];
  const float* bg = (const float*)d_in[7];
  const float* W2 = (const float*)d_in[8];
  const float* b2 = (const float*)d_in[9];
  const float* W3 = (const float*)d_in[10];
  const float* b3 = (const float*)d_in[11];

  const int N = in_sizes[0] / 128;
  const int E = in_sizes[1] / 2;
  const int* src = ei;
  const int* dst = ei + E;

  char* base = (char*)d_ws;
  size_t off = 0;
  auto alloc = [&](size_t bytes) {
    void* p = base + off;
    off = (off + bytes + 255) & ~(size_t)255;
    return p;
  };
  int*   cnt    = (int*)alloc((size_t)N * 4);
  int*   bsums  = (int*)alloc(1024 * 4);
  int*   rowptr = (int*)alloc((size_t)(N + 1) * 4);
  int*   csr    = (int*)alloc((size_t)E * 4);
  float* dinv   = (float*)alloc((size_t)N * 4);
  float* as_    = (float*)alloc((size_t)N * 8 * 4);
  float* ad_    = (float*)alloc((size_t)N * 8 * 4);
  float* bufA   = (float*)alloc((size_t)N * 64 * 4);
  float* bufB   = (float*)alloc((size_t)N * 64 * 4);
  (void)ws_size; (void)n_in; (void)out_size;

  const int gN    = (N + 255) / 256;
  const int gN8   = (N * 8 + 255) / 256;
  const int gMM   = (N + 15) / 16;
  const int gNode = (N + 3) / 4;
  const int nb    = (N + 1023) / 1024;
  const int nbin  = (N + R_CAP - 1) / R_CAP;

  // ---- CSR build ----
  count_bin_kernel<<<nbin, 1024, 0, stream>>>(dst, cnt, N, E);
  scan1_kernel<<<nb, 1024, 0, stream>>>(cnt, bsums, N);
  scan2_kernel<<<1, 1024, 0, stream>>>(bsums, nb);
  scan3_kernel<<<nb, 1024, 0, stream>>>(cnt, bsums, rowptr, N, E);
  dinv_kernel<<<gN, 256, 0, stream>>>(rowptr, dinv, N);
  scatter_bin_kernel<<<nbin, 1024, 0, stream>>>(src, dst, rowptr, csr, N, E);

  // ---- GCN0 ----
  matmul_kernel<128, true><<<gMM, 256, 0, stream>>>(x, W0, dinv, bufA, N);
  gcn_layer_kernel<true><<<gNode, 256, 0, stream>>>(rowptr, csr, bufA, dinv, b0, bufB, N);

  // ---- GAT ----
  matmul_kernel<64, false><<<gMM, 256, 0, stream>>>(bufB, Wg, nullptr, bufA, N);
  gat_alpha_kernel<<<gN8, 256, 0, stream>>>(bufA, av, aw, as_, ad_, N * 8);
  gat_layer_kernel<<<gNode, 256, 0, stream>>>(rowptr, csr, bufA, as_, ad_, bg, bufB, N);

  // ---- GCN2 ----
  matmul_kernel<64, true><<<gMM, 256, 0, stream>>>(bufB, W2, dinv, bufA, N);
  gcn_layer_kernel<true><<<gNode, 256, 0, stream>>>(rowptr, csr, bufA, dinv, b2, bufB, N);

  // ---- GCN3: final layer, no relu, FLOAT32 out (the nine-round bug) ----
  matmul_kernel<64, true><<<gMM, 256, 0, stream>>>(bufB, W3, dinv, bufA, N);
  gcn_layer_kernel<false><<<gNode, 256, 0, stream>>>(rowptr, csr, bufA, dinv, b3,
                                                     (float*)d_out, N);
}